// Round 4
// baseline (100.441 us; speedup 1.0000x reference)
//
#include <hip/hip_runtime.h>
#include <math.h>

#define NU 100000
#define NI 50000
#define DK 256      // DU == DI
#define EN 128      // E
#define BB 8192
#define TT 24

typedef short short8 __attribute__((ext_vector_type(8)));
typedef float f32x4  __attribute__((ext_vector_type(4)));

// ---- d_ws layout (bytes) ----
#define WPACK_SHORTS 114688
#define WP_OFF     0
#define OWNER_OFF  229376                 // 100000 ints
#define NTAB_OFF   629376                 // 50000*128 bf16 = 12.8 MB
#define NPART_OFF  13429376               // 8192*128 f32  = 4 MB

// wpack element offsets (bf16 shorts, all [N][K] k-contiguous)
#define OFF_IWT   0        // 128x256
#define OFF_UWT   32768    // 128x256
#define OFF_AW1UT 65536    // 128x128 (aW1 rows 0..127   -> neigh part)
#define OFF_AW1LT 81920    // 128x128 (aW1 rows 128..255 -> node part)
#define OFF_AW2T  98304    // 128x128

__device__ __forceinline__ unsigned short f2b(float x) {
    unsigned int u = __float_as_uint(x);
    u = (u + 0x7FFFu + ((u >> 16) & 1u)) >> 16;   // RNE, finite inputs
    return (unsigned short)u;
}
__device__ __forceinline__ float b2f(unsigned short v) {
    return __uint_as_float(((unsigned int)v) << 16);
}

#define MFMA(a, b, c) __builtin_amdgcn_mfma_f32_16x16x32_bf16((a), (b), (c), 0, 0, 0)
#define LDROW(buf, stride, row, k) \
    (*reinterpret_cast<const short8*>(reinterpret_cast<const char*>(buf) + (row) * (stride) + (k) * 2))

// ---- fast zero of out_embed (51.2 MB) : grid-stride dwordx4 stores ----
__global__ __launch_bounds__(256)
void zero_embed(float4* __restrict__ p, int n16) {
    int i = blockIdx.x * 256 + threadIdx.x;
    int stride = gridDim.x * 256;
    float4 z = {0.f, 0.f, 0.f, 0.f};
    for (; i < n16; i += stride) p[i] = z;
}

// ---- owner: scatter-reset batch nodes to -1, then last-occurrence-wins ----
__global__ void owner_reset(const int* __restrict__ nodes, int* __restrict__ owner) {
    int b = blockIdx.x * blockDim.x + threadIdx.x;
    if (b < BB) owner[nodes[b]] = -1;
}
__global__ void owner_kernel(const int* __restrict__ nodes, int* __restrict__ owner) {
    int b = blockIdx.x * blockDim.x + threadIdx.x;
    if (b < BB) atomicMax(&owner[nodes[b]], b);
}

__global__ void pack_weights(const float* __restrict__ uW, const float* __restrict__ iW,
                             const float* __restrict__ aW1, const float* __restrict__ aW2,
                             short* __restrict__ wp) {
    int i = blockIdx.x * 256 + threadIdx.x;
    if (i >= WPACK_SHORTS) return;
    float v;
    if (i < 32768)      { int j = i;         int n = j >> 8, k = j & 255; v = iW[k * EN + n]; }
    else if (i < 65536) { int j = i - 32768; int n = j >> 8, k = j & 255; v = uW[k * EN + n]; }
    else if (i < 81920) { int j = i - 65536; int n = j >> 7, k = j & 127; v = aW1[k * EN + n]; }
    else if (i < 98304) { int j = i - 81920; int n = j >> 7, k = j & 127; v = aW1[(128 + k) * EN + n]; }
    else                { int j = i - 98304; int n = j >> 7, k = j & 127; v = aW2[k * EN + n]; }
    wp[i] = (short)f2b(v);
}

// ---- K3: neighs_all[NI][128] bf16 = i_weight @ iW + ib (dense, coalesced) ----
__global__ __launch_bounds__(256, 2)
void neighs_all_kernel(const float* __restrict__ i_weight, const float* __restrict__ ib,
                       const short* __restrict__ wp, short* __restrict__ ntab)
{
    __shared__ __align__(16) short sA[64 * 264];   // 33792 B, 528B row stride
    __shared__ __align__(16) short sO[64 * 132];   // 16896 B, 264B row stride
    const int tid = threadIdx.x;
    const int r0  = blockIdx.x * 64;
    const int nrows = (NI - r0 < 64) ? (NI - r0) : 64;

    for (int task = tid; task < 64 * 32; task += 256) {
        int row = task >> 5, c = task & 31;
        if (row < nrows) {
            const float* src = i_weight + (size_t)(r0 + row) * DK + c * 8;
            float4 f0 = *(const float4*)src;
            float4 f1 = *(const float4*)(src + 4);
            short8 o;
            o[0]=f2b(f0.x); o[1]=f2b(f0.y); o[2]=f2b(f0.z); o[3]=f2b(f0.w);
            o[4]=f2b(f1.x); o[5]=f2b(f1.y); o[6]=f2b(f1.z); o[7]=f2b(f1.w);
            *reinterpret_cast<short8*>(reinterpret_cast<char*>(sA) + row * 528 + c * 16) = o;
        }
    }
    __syncthreads();

    const int l = tid & 63, lr = l & 15, lq = l >> 4, n0 = (tid >> 6) * 32;
    const int kA = lq * 8, nc0 = n0 + lr, nc1 = n0 + 16 + lr;
    const short* iWt = wp + OFF_IWT;

    f32x4 acc[4][2];
    #pragma unroll
    for (int m = 0; m < 4; ++m) { acc[m][0] = {0.f,0.f,0.f,0.f}; acc[m][1] = {0.f,0.f,0.f,0.f}; }
    #pragma unroll
    for (int ks = 0; ks < 8; ++ks) {
        int k = ks * 32 + kA;
        short8 w0 = *reinterpret_cast<const short8*>(iWt + nc0 * DK + k);
        short8 w1 = *reinterpret_cast<const short8*>(iWt + nc1 * DK + k);
        #pragma unroll
        for (int m = 0; m < 4; ++m) {
            short8 a = LDROW(sA, 528, m * 16 + lr, k);
            acc[m][0] = MFMA(a, w0, acc[m][0]);
            acc[m][1] = MFMA(a, w1, acc[m][1]);
        }
    }
    {
        float ib0 = ib[nc0], ib1 = ib[nc1];
        #pragma unroll
        for (int m = 0; m < 4; ++m)
            #pragma unroll
            for (int nt = 0; nt < 2; ++nt) {
                int n = nt ? nc1 : nc0;
                float bv = nt ? ib1 : ib0;
                #pragma unroll
                for (int r = 0; r < 4; ++r) {
                    int row = m * 16 + lq * 4 + r;
                    *reinterpret_cast<short*>(reinterpret_cast<char*>(sO) + row * 264 + n * 2)
                        = (short)f2b(acc[m][nt][r] + bv);
                }
            }
    }
    __syncthreads();
    for (int g = tid; g < nrows * 16; g += 256) {
        int row = g >> 4, s = g & 15;
        short8 v = *reinterpret_cast<const short8*>(reinterpret_cast<const char*>(sO) + row * 264 + s * 16);
        *reinterpret_cast<short8*>(ntab + (size_t)(r0 + row) * EN + s * 8) = v;
    }
}

// ---- K4: nf = u_weight[nodes] @ uW + ub (write out_nf); npart = nf @ aW1L + ab1 ----
__global__ __launch_bounds__(256, 2)
void nf_npart_kernel(const int* __restrict__ nodes, const float* __restrict__ u_weight,
                     const float* __restrict__ ub, const float* __restrict__ ab1,
                     const short* __restrict__ wp,
                     float* __restrict__ out_nf, float* __restrict__ npart)
{
    __shared__ __align__(16) short sU[64 * 264];   // 33792 B
    __shared__ __align__(16) short sNf[64 * 136];  // 17408 B, 272B stride
    __shared__ int sNd[64];
    const int tid = threadIdx.x;
    const int r0  = blockIdx.x * 64;

    if (tid < 64) sNd[tid] = nodes[r0 + tid];
    __syncthreads();

    for (int task = tid; task < 64 * 32; task += 256) {
        int row = task >> 5, c = task & 31;
        const float* src = u_weight + (size_t)sNd[row] * DK + c * 8;
        float4 f0 = *(const float4*)src;
        float4 f1 = *(const float4*)(src + 4);
        short8 o;
        o[0]=f2b(f0.x); o[1]=f2b(f0.y); o[2]=f2b(f0.z); o[3]=f2b(f0.w);
        o[4]=f2b(f1.x); o[5]=f2b(f1.y); o[6]=f2b(f1.z); o[7]=f2b(f1.w);
        *reinterpret_cast<short8*>(reinterpret_cast<char*>(sU) + row * 528 + c * 16) = o;
    }
    __syncthreads();

    const int l = tid & 63, lr = l & 15, lq = l >> 4, n0 = (tid >> 6) * 32;
    const int kA = lq * 8, nc0 = n0 + lr, nc1 = n0 + 16 + lr;
    const short* uWt   = wp + OFF_UWT;
    const short* aW1Lt = wp + OFF_AW1LT;

    f32x4 acc[4][2];
    #pragma unroll
    for (int m = 0; m < 4; ++m) { acc[m][0] = {0.f,0.f,0.f,0.f}; acc[m][1] = {0.f,0.f,0.f,0.f}; }
    #pragma unroll
    for (int ks = 0; ks < 8; ++ks) {
        int k = ks * 32 + kA;
        short8 w0 = *reinterpret_cast<const short8*>(uWt + nc0 * DK + k);
        short8 w1 = *reinterpret_cast<const short8*>(uWt + nc1 * DK + k);
        #pragma unroll
        for (int m = 0; m < 4; ++m) {
            short8 a = LDROW(sU, 528, m * 16 + lr, k);
            acc[m][0] = MFMA(a, w0, acc[m][0]);
            acc[m][1] = MFMA(a, w1, acc[m][1]);
        }
    }
    {
        float b0v = ub[nc0], b1v = ub[nc1];
        #pragma unroll
        for (int m = 0; m < 4; ++m)
            #pragma unroll
            for (int nt = 0; nt < 2; ++nt) {
                int n = nt ? nc1 : nc0;
                float bv = nt ? b1v : b0v;
                #pragma unroll
                for (int r = 0; r < 4; ++r) {
                    int row = m * 16 + lq * 4 + r;
                    float v = acc[m][nt][r] + bv;
                    out_nf[(size_t)(r0 + row) * EN + n] = v;
                    *reinterpret_cast<short*>(reinterpret_cast<char*>(sNf) + row * 272 + n * 2)
                        = (short)f2b(v);
                }
            }
    }
    __syncthreads();

    f32x4 ap[4][2];
    #pragma unroll
    for (int m = 0; m < 4; ++m) { ap[m][0] = {0.f,0.f,0.f,0.f}; ap[m][1] = {0.f,0.f,0.f,0.f}; }
    #pragma unroll
    for (int ks = 0; ks < 4; ++ks) {
        int k = ks * 32 + kA;
        short8 w0 = *reinterpret_cast<const short8*>(aW1Lt + nc0 * EN + k);
        short8 w1 = *reinterpret_cast<const short8*>(aW1Lt + nc1 * EN + k);
        #pragma unroll
        for (int m = 0; m < 4; ++m) {
            short8 a = LDROW(sNf, 272, m * 16 + lr, k);
            ap[m][0] = MFMA(a, w0, ap[m][0]);
            ap[m][1] = MFMA(a, w1, ap[m][1]);
        }
    }
    {
        float b0v = ab1[nc0], b1v = ab1[nc1];
        #pragma unroll
        for (int m = 0; m < 4; ++m)
            #pragma unroll
            for (int nt = 0; nt < 2; ++nt) {
                int n = nt ? nc1 : nc0;
                float bv = nt ? b1v : b0v;
                #pragma unroll
                for (int r = 0; r < 4; ++r) {
                    int row = m * 16 + lq * 4 + r;
                    npart[(size_t)(r0 + row) * EN + n] = ap[m][nt][r] + bv;
                }
            }
    }
}

// ---- K5: per 2 batch rows: gather neighs -> h1 -> h2 -> logits -> softmax -> agg ----
__global__ __launch_bounds__(256, 4)
void attn_kernel(const int* __restrict__ nodes, const int* __restrict__ neigh_idx,
                 const float* __restrict__ ab2, const float* __restrict__ aW3,
                 const float* __restrict__ ab3, const short* __restrict__ wp,
                 const short* __restrict__ ntab, const float* __restrict__ npart,
                 const int* __restrict__ owner, float* __restrict__ out_embed)
{
    __shared__ __align__(16) short sNg[48 * 136];  // 13056 B, 272B stride
    __shared__ __align__(16) short sH1[48 * 136];  // 13056 B
    __shared__ float sNp[256];
    __shared__ float sW3[EN];
    __shared__ float sLogP[4][48];
    __shared__ float sLog[48];
    __shared__ float sAtt[48];
    __shared__ int   sIdx[48];
    __shared__ int   sNode[2];

    const int tid = threadIdx.x;
    const int b0  = blockIdx.x * 2;

    if (tid < 48) sIdx[tid]  = neigh_idx[b0 * TT + tid];
    if (tid < 2)  sNode[tid] = nodes[b0 + tid];
    if (tid < EN) sW3[tid]   = aW3[tid];
    sNp[tid] = npart[(size_t)b0 * EN + tid];
    __syncthreads();

    // stage 48 neighbor rows (256B bf16 each) from the hot table
    for (int task = tid; task < 48 * 16; task += 256) {
        int row = task >> 4, s = task & 15;
        short8 v = *reinterpret_cast<const short8*>(ntab + (size_t)sIdx[row] * EN + s * 8);
        *reinterpret_cast<short8*>(reinterpret_cast<char*>(sNg) + row * 272 + s * 16) = v;
    }
    __syncthreads();

    const int l = tid & 63, lr = l & 15, lq = l >> 4;
    const int wid = tid >> 6, n0 = wid * 32;
    const int kA = lq * 8, nc0 = n0 + lr, nc1 = n0 + 16 + lr;
    const short* aW1Ut = wp + OFF_AW1UT;
    const short* aW2t  = wp + OFF_AW2T;

    // h1 = relu(neighs @ aW1U + npart)
    f32x4 a1[3][2];
    #pragma unroll
    for (int m = 0; m < 3; ++m) { a1[m][0] = {0.f,0.f,0.f,0.f}; a1[m][1] = {0.f,0.f,0.f,0.f}; }
    #pragma unroll
    for (int ks = 0; ks < 4; ++ks) {
        int k = ks * 32 + kA;
        short8 w0 = *reinterpret_cast<const short8*>(aW1Ut + nc0 * EN + k);
        short8 w1 = *reinterpret_cast<const short8*>(aW1Ut + nc1 * EN + k);
        #pragma unroll
        for (int m = 0; m < 3; ++m) {
            short8 a = LDROW(sNg, 272, m * 16 + lr, k);
            a1[m][0] = MFMA(a, w0, a1[m][0]);
            a1[m][1] = MFMA(a, w1, a1[m][1]);
        }
    }
    #pragma unroll
    for (int m = 0; m < 3; ++m)
        #pragma unroll
        for (int nt = 0; nt < 2; ++nt) {
            int n = nt ? nc1 : nc0;
            #pragma unroll
            for (int r = 0; r < 4; ++r) {
                int row = m * 16 + lq * 4 + r;
                int g = (row >= TT) ? 1 : 0;
                float v = fmaxf(a1[m][nt][r] + sNp[g * EN + n], 0.f);
                *reinterpret_cast<short*>(reinterpret_cast<char*>(sH1) + row * 272 + n * 2)
                    = (short)f2b(v);
            }
        }
    __syncthreads();

    // h2 = relu(h1 @ aW2 + ab2); logits accumulated in-register
    f32x4 a2[3][2];
    #pragma unroll
    for (int m = 0; m < 3; ++m) { a2[m][0] = {0.f,0.f,0.f,0.f}; a2[m][1] = {0.f,0.f,0.f,0.f}; }
    #pragma unroll
    for (int ks = 0; ks < 4; ++ks) {
        int k = ks * 32 + kA;
        short8 w0 = *reinterpret_cast<const short8*>(aW2t + nc0 * EN + k);
        short8 w1 = *reinterpret_cast<const short8*>(aW2t + nc1 * EN + k);
        #pragma unroll
        for (int m = 0; m < 3; ++m) {
            short8 a = LDROW(sH1, 272, m * 16 + lr, k);
            a2[m][0] = MFMA(a, w0, a2[m][0]);
            a2[m][1] = MFMA(a, w1, a2[m][1]);
        }
    }
    {
        float b0v = ab2[nc0], b1v = ab2[nc1];
        float w3a = sW3[nc0], w3b = sW3[nc1];
        #pragma unroll
        for (int m = 0; m < 3; ++m) {
            float lp[4];
            #pragma unroll
            for (int r = 0; r < 4; ++r) {
                float v0 = fmaxf(a2[m][0][r] + b0v, 0.f);
                float v1 = fmaxf(a2[m][1][r] + b1v, 0.f);
                lp[r] = v0 * w3a + v1 * w3b;
            }
            #pragma unroll
            for (int r = 0; r < 4; ++r) {
                float v = lp[r];
                v += __shfl_xor(v, 1, 16);
                v += __shfl_xor(v, 2, 16);
                v += __shfl_xor(v, 4, 16);
                v += __shfl_xor(v, 8, 16);
                if (lr == 0) sLogP[wid][m * 16 + lq * 4 + r] = v;
            }
        }
    }
    __syncthreads();
    if (tid < 48)
        sLog[tid] = sLogP[0][tid] + sLogP[1][tid] + sLogP[2][tid] + sLogP[3][tid] + ab3[0];
    __syncthreads();

    // softmax over T=24, two groups in wave 0
    if (tid < 64) {
        int g = tid >> 5, tt = tid & 31;
        float v = (tt < TT) ? sLog[g * TT + tt] : -1e30f;
        float mx = v;
        #pragma unroll
        for (int d = 16; d > 0; d >>= 1) mx = fmaxf(mx, __shfl_xor(mx, d, 32));
        float p = (tt < TT) ? __expf(v - mx) : 0.f;
        float s = p;
        #pragma unroll
        for (int d = 16; d > 0; d >>= 1) s += __shfl_xor(s, d, 32);
        if (tt < TT) sAtt[g * TT + tt] = p / s;
    }
    __syncthreads();

    // agg + scatter
    {
        int g = tid >> 7, e = tid & 127;
        float a = 0.f;
        #pragma unroll
        for (int t = 0; t < TT; ++t) {
            unsigned short nv = *reinterpret_cast<const unsigned short*>(
                reinterpret_cast<const char*>(sNg) + (g * TT + t) * 272 + e * 2);
            a += sAtt[g * TT + t] * b2f(nv);
        }
        int node = sNode[g];
        if (owner[node] == b0 + g)
            out_embed[(size_t)node * EN + e] = a;
    }
}

extern "C" void kernel_launch(void* const* d_in, const int* in_sizes, int n_in,
                              void* d_out, int out_size, void* d_ws, size_t ws_size,
                              hipStream_t stream) {
    const int*   nodes     = (const int*)d_in[0];
    const int*   neigh_idx = (const int*)d_in[1];
    const float* u_weight  = (const float*)d_in[2];
    const float* i_weight  = (const float*)d_in[3];
    const float* uW  = (const float*)d_in[4];
    const float* ub  = (const float*)d_in[5];
    const float* iW  = (const float*)d_in[6];
    const float* ib  = (const float*)d_in[7];
    const float* aW1 = (const float*)d_in[8];
    const float* ab1 = (const float*)d_in[9];
    const float* aW2 = (const float*)d_in[10];
    const float* ab2 = (const float*)d_in[11];
    const float* aW3 = (const float*)d_in[12];
    const float* ab3 = (const float*)d_in[13];

    float* out_nf    = (float*)d_out;
    float* out_embed = out_nf + (size_t)BB * EN;

    char*  ws    = (char*)d_ws;
    short* wpack = (short*)(ws + WP_OFF);
    int*   owner = (int*)(ws + OWNER_OFF);
    short* ntab  = (short*)(ws + NTAB_OFF);
    float* npart = (float*)(ws + NPART_OFF);

    // fast zero of the scatter target (replaces slow runtime fillBuffer)
    zero_embed<<<2048, 256, 0, stream>>>((float4*)out_embed, NU * EN / 4);
    // owner: reset only batch-touched entries, then last-occurrence-wins
    owner_reset<<<(BB + 255) / 256, 256, 0, stream>>>(nodes, owner);
    owner_kernel<<<(BB + 255) / 256, 256, 0, stream>>>(nodes, owner);
    pack_weights<<<(WPACK_SHORTS + 255) / 256, 256, 0, stream>>>(uW, iW, aW1, aW2, wpack);
    neighs_all_kernel<<<(NI + 63) / 64, 256, 0, stream>>>(i_weight, ib, wpack, ntab);
    nf_npart_kernel<<<BB / 64, 256, 0, stream>>>(nodes, u_weight, ub, ab1, wpack, out_nf, npart);
    attn_kernel<<<BB / 2, 256, 0, stream>>>(nodes, neigh_idx, ab2, aW3, ab3,
                                            wpack, ntab, npart, owner, out_embed);
}

// Round 5
// 84.965 us; speedup vs baseline: 1.1821x; 1.1821x over previous
//
#include <hip/hip_runtime.h>
#include <math.h>

#define NU 100000
#define NI 50000
#define DK 256      // DU == DI
#define EN 128      // E
#define BB 8192
#define TT 24

typedef short short8 __attribute__((ext_vector_type(8)));
typedef float f32x4  __attribute__((ext_vector_type(4)));

// ---- d_ws layout (bytes) ----
#define WPACK_SHORTS 114688
#define WP_OFF     0
#define OWNER_OFF  229376                 // 100000 ints
#define NTAB_OFF   629376                 // 50000*128 bf16 = 12.8 MB
#define NPART_OFF  13429376               // 8192*128 f32  = 4 MB

// wpack element offsets (bf16 shorts, all [N][K] k-contiguous)
#define OFF_IWT   0        // 128x256
#define OFF_UWT   32768    // 128x256
#define OFF_AW1UT 65536    // 128x128 (aW1 rows 0..127   -> neigh part)
#define OFF_AW1LT 81920    // 128x128 (aW1 rows 128..255 -> node part)
#define OFF_AW2T  98304    // 128x128

#define NBLK_NEIGH 782     // ceil(NI/64)
#define NBLK_NF    128     // BB/64

__device__ __forceinline__ unsigned short f2b(float x) {
    unsigned int u = __float_as_uint(x);
    u = (u + 0x7FFFu + ((u >> 16) & 1u)) >> 16;   // RNE, finite inputs
    return (unsigned short)u;
}
__device__ __forceinline__ float b2f(unsigned short v) {
    return __uint_as_float(((unsigned int)v) << 16);
}

#define MFMA(a, b, c) __builtin_amdgcn_mfma_f32_16x16x32_bf16((a), (b), (c), 0, 0, 0)
#define LDROW(buf, stride, row, k) \
    (*reinterpret_cast<const short8*>(reinterpret_cast<const char*>(buf) + (row) * (stride) + (k) * 2))

// ---- K1: zero out_embed + pack weights + owner reset, all grid-stride ----
__global__ __launch_bounds__(256)
void prep_kernel(const int* __restrict__ nodes,
                 const float* __restrict__ uW, const float* __restrict__ iW,
                 const float* __restrict__ aW1, const float* __restrict__ aW2,
                 short* __restrict__ wp, int* __restrict__ owner,
                 float4* __restrict__ embed4, int n16)
{
    const int gid = blockIdx.x * 256 + threadIdx.x;
    const int gsz = gridDim.x * 256;
    float4 z = {0.f, 0.f, 0.f, 0.f};
    for (int i = gid; i < n16; i += gsz) embed4[i] = z;
    for (int i = gid; i < WPACK_SHORTS; i += gsz) {
        float v;
        if (i < 32768)      { int j = i;         int n = j >> 8, k = j & 255; v = iW[k * EN + n]; }
        else if (i < 65536) { int j = i - 32768; int n = j >> 8, k = j & 255; v = uW[k * EN + n]; }
        else if (i < 81920) { int j = i - 65536; int n = j >> 7, k = j & 127; v = aW1[k * EN + n]; }
        else if (i < 98304) { int j = i - 81920; int n = j >> 7, k = j & 127; v = aW1[(128 + k) * EN + n]; }
        else                { int j = i - 98304; int n = j >> 7, k = j & 127; v = aW2[k * EN + n]; }
        wp[i] = (short)f2b(v);
    }
    for (int i = gid; i < BB; i += gsz) owner[nodes[i]] = -1;
}

// ---- K2: union kernel: blocks [0,782) neighs table; [782,910) nf/npart (+owner max) ----
__global__ __launch_bounds__(256, 4)
void embed_kernel(const int* __restrict__ nodes,
                  const float* __restrict__ u_weight, const float* __restrict__ i_weight,
                  const float* __restrict__ ub, const float* __restrict__ ib,
                  const float* __restrict__ ab1,
                  const short* __restrict__ wp, int* __restrict__ owner,
                  short* __restrict__ ntab, float* __restrict__ out_nf,
                  float* __restrict__ npart)
{
    __shared__ __align__(16) char smem[33792];   // A-staging (528B x 64 rows); overlaid by outputs
    __shared__ int sNd[64];

    const int tid = threadIdx.x;
    const int l = tid & 63, lr = l & 15, lq = l >> 4, n0 = (tid >> 6) * 32;
    const int kA = lq * 8, nc0 = n0 + lr, nc1 = n0 + 16 + lr;

    if (blockIdx.x < NBLK_NEIGH) {
        // ======== neighs path: ntab[r] = bf16(i_weight[r] @ iW + ib) ========
        const int r0 = blockIdx.x * 64;
        const int nrows = (NI - r0 < 64) ? (NI - r0) : 64;

        for (int task = tid; task < 64 * 32; task += 256) {
            int row = task >> 5, c = task & 31;
            if (row < nrows) {
                const float* src = i_weight + (size_t)(r0 + row) * DK + c * 8;
                float4 f0 = *(const float4*)src;
                float4 f1 = *(const float4*)(src + 4);
                short8 o;
                o[0]=f2b(f0.x); o[1]=f2b(f0.y); o[2]=f2b(f0.z); o[3]=f2b(f0.w);
                o[4]=f2b(f1.x); o[5]=f2b(f1.y); o[6]=f2b(f1.z); o[7]=f2b(f1.w);
                *reinterpret_cast<short8*>(smem + row * 528 + c * 16) = o;
            }
        }
        __syncthreads();

        const short* iWt = wp + OFF_IWT;
        f32x4 acc[4][2];
        #pragma unroll
        for (int m = 0; m < 4; ++m) { acc[m][0] = {0.f,0.f,0.f,0.f}; acc[m][1] = {0.f,0.f,0.f,0.f}; }
        #pragma unroll
        for (int ks = 0; ks < 8; ++ks) {
            int k = ks * 32 + kA;
            short8 w0 = *reinterpret_cast<const short8*>(iWt + nc0 * DK + k);
            short8 w1 = *reinterpret_cast<const short8*>(iWt + nc1 * DK + k);
            #pragma unroll
            for (int m = 0; m < 4; ++m) {
                short8 a = LDROW(smem, 528, m * 16 + lr, k);
                acc[m][0] = MFMA(a, w0, acc[m][0]);
                acc[m][1] = MFMA(a, w1, acc[m][1]);
            }
        }
        __syncthreads();   // all reads of A done; overlay output tile (264B stride)
        {
            float ib0 = ib[nc0], ib1 = ib[nc1];
            #pragma unroll
            for (int m = 0; m < 4; ++m)
                #pragma unroll
                for (int nt = 0; nt < 2; ++nt) {
                    int n = nt ? nc1 : nc0;
                    float bv = nt ? ib1 : ib0;
                    #pragma unroll
                    for (int r = 0; r < 4; ++r) {
                        int row = m * 16 + lq * 4 + r;
                        *reinterpret_cast<short*>(smem + row * 264 + n * 2)
                            = (short)f2b(acc[m][nt][r] + bv);
                    }
                }
        }
        __syncthreads();
        for (int g = tid; g < nrows * 16; g += 256) {
            int row = g >> 4, s = g & 15;
            short8 v = *reinterpret_cast<const short8*>(smem + row * 264 + s * 16);
            *reinterpret_cast<short8*>(ntab + (size_t)(r0 + row) * EN + s * 8) = v;
        }
    } else {
        // ======== nf path: out_nf + npart for 64 batch rows; also owner atomicMax ========
        const int bblk = blockIdx.x - NBLK_NEIGH;
        const int r0 = bblk * 64;
        {
            int bq = bblk * 256 + tid;
            if (bq < BB) atomicMax(&owner[nodes[bq]], bq);
        }
        if (tid < 64) sNd[tid] = nodes[r0 + tid];
        __syncthreads();

        for (int task = tid; task < 64 * 32; task += 256) {
            int row = task >> 5, c = task & 31;
            const float* src = u_weight + (size_t)sNd[row] * DK + c * 8;
            float4 f0 = *(const float4*)src;
            float4 f1 = *(const float4*)(src + 4);
            short8 o;
            o[0]=f2b(f0.x); o[1]=f2b(f0.y); o[2]=f2b(f0.z); o[3]=f2b(f0.w);
            o[4]=f2b(f1.x); o[5]=f2b(f1.y); o[6]=f2b(f1.z); o[7]=f2b(f1.w);
            *reinterpret_cast<short8*>(smem + row * 528 + c * 16) = o;
        }
        __syncthreads();

        const short* uWt   = wp + OFF_UWT;
        const short* aW1Lt = wp + OFF_AW1LT;

        f32x4 acc[4][2];
        #pragma unroll
        for (int m = 0; m < 4; ++m) { acc[m][0] = {0.f,0.f,0.f,0.f}; acc[m][1] = {0.f,0.f,0.f,0.f}; }
        #pragma unroll
        for (int ks = 0; ks < 8; ++ks) {
            int k = ks * 32 + kA;
            short8 w0 = *reinterpret_cast<const short8*>(uWt + nc0 * DK + k);
            short8 w1 = *reinterpret_cast<const short8*>(uWt + nc1 * DK + k);
            #pragma unroll
            for (int m = 0; m < 4; ++m) {
                short8 a = LDROW(smem, 528, m * 16 + lr, k);
                acc[m][0] = MFMA(a, w0, acc[m][0]);
                acc[m][1] = MFMA(a, w1, acc[m][1]);
            }
        }
        __syncthreads();   // A reads done; overlay bf16 nf tile (272B stride)
        {
            float b0v = ub[nc0], b1v = ub[nc1];
            #pragma unroll
            for (int m = 0; m < 4; ++m)
                #pragma unroll
                for (int nt = 0; nt < 2; ++nt) {
                    int n = nt ? nc1 : nc0;
                    float bv = nt ? b1v : b0v;
                    #pragma unroll
                    for (int r = 0; r < 4; ++r) {
                        int row = m * 16 + lq * 4 + r;
                        float v = acc[m][nt][r] + bv;
                        out_nf[(size_t)(r0 + row) * EN + n] = v;
                        *reinterpret_cast<short*>(smem + row * 272 + n * 2) = (short)f2b(v);
                    }
                }
        }
        __syncthreads();

        f32x4 ap[4][2];
        #pragma unroll
        for (int m = 0; m < 4; ++m) { ap[m][0] = {0.f,0.f,0.f,0.f}; ap[m][1] = {0.f,0.f,0.f,0.f}; }
        #pragma unroll
        for (int ks = 0; ks < 4; ++ks) {
            int k = ks * 32 + kA;
            short8 w0 = *reinterpret_cast<const short8*>(aW1Lt + nc0 * EN + k);
            short8 w1 = *reinterpret_cast<const short8*>(aW1Lt + nc1 * EN + k);
            #pragma unroll
            for (int m = 0; m < 4; ++m) {
                short8 a = LDROW(smem, 272, m * 16 + lr, k);
                ap[m][0] = MFMA(a, w0, ap[m][0]);
                ap[m][1] = MFMA(a, w1, ap[m][1]);
            }
        }
        {
            float b0v = ab1[nc0], b1v = ab1[nc1];
            #pragma unroll
            for (int m = 0; m < 4; ++m)
                #pragma unroll
                for (int nt = 0; nt < 2; ++nt) {
                    int n = nt ? nc1 : nc0;
                    float bv = nt ? b1v : b0v;
                    #pragma unroll
                    for (int r = 0; r < 4; ++r) {
                        int row = m * 16 + lq * 4 + r;
                        npart[(size_t)(r0 + row) * EN + n] = ap[m][nt][r] + bv;
                    }
                }
        }
    }
}

// ---- K3: per 2 batch rows: gather neighs -> h1 -> h2 -> logits -> softmax -> agg ----
__global__ __launch_bounds__(256, 4)
void attn_kernel(const int* __restrict__ nodes, const int* __restrict__ neigh_idx,
                 const float* __restrict__ ab2, const float* __restrict__ aW3,
                 const float* __restrict__ ab3, const short* __restrict__ wp,
                 const short* __restrict__ ntab, const float* __restrict__ npart,
                 const int* __restrict__ owner, float* __restrict__ out_embed)
{
    __shared__ __align__(16) short sNg[48 * 136];  // 13056 B, 272B stride
    __shared__ __align__(16) short sH1[48 * 136];  // 13056 B
    __shared__ float sNp[256];
    __shared__ float sW3[EN];
    __shared__ float sLogP[4][48];
    __shared__ float sLog[48];
    __shared__ float sAtt[48];
    __shared__ int   sIdx[48];
    __shared__ int   sNode[2];

    const int tid = threadIdx.x;
    const int b0  = blockIdx.x * 2;

    if (tid < 48) sIdx[tid]  = neigh_idx[b0 * TT + tid];
    if (tid < 2)  sNode[tid] = nodes[b0 + tid];
    if (tid < EN) sW3[tid]   = aW3[tid];
    sNp[tid] = npart[(size_t)b0 * EN + tid];
    __syncthreads();

    for (int task = tid; task < 48 * 16; task += 256) {
        int row = task >> 4, s = task & 15;
        short8 v = *reinterpret_cast<const short8*>(ntab + (size_t)sIdx[row] * EN + s * 8);
        *reinterpret_cast<short8*>(reinterpret_cast<char*>(sNg) + row * 272 + s * 16) = v;
    }
    __syncthreads();

    const int l = tid & 63, lr = l & 15, lq = l >> 4;
    const int wid = tid >> 6, n0 = wid * 32;
    const int kA = lq * 8, nc0 = n0 + lr, nc1 = n0 + 16 + lr;
    const short* aW1Ut = wp + OFF_AW1UT;
    const short* aW2t  = wp + OFF_AW2T;

    f32x4 a1[3][2];
    #pragma unroll
    for (int m = 0; m < 3; ++m) { a1[m][0] = {0.f,0.f,0.f,0.f}; a1[m][1] = {0.f,0.f,0.f,0.f}; }
    #pragma unroll
    for (int ks = 0; ks < 4; ++ks) {
        int k = ks * 32 + kA;
        short8 w0 = *reinterpret_cast<const short8*>(aW1Ut + nc0 * EN + k);
        short8 w1 = *reinterpret_cast<const short8*>(aW1Ut + nc1 * EN + k);
        #pragma unroll
        for (int m = 0; m < 3; ++m) {
            short8 a = LDROW(sNg, 272, m * 16 + lr, k);
            a1[m][0] = MFMA(a, w0, a1[m][0]);
            a1[m][1] = MFMA(a, w1, a1[m][1]);
        }
    }
    #pragma unroll
    for (int m = 0; m < 3; ++m)
        #pragma unroll
        for (int nt = 0; nt < 2; ++nt) {
            int n = nt ? nc1 : nc0;
            #pragma unroll
            for (int r = 0; r < 4; ++r) {
                int row = m * 16 + lq * 4 + r;
                int g = (row >= TT) ? 1 : 0;
                float v = fmaxf(a1[m][nt][r] + sNp[g * EN + n], 0.f);
                *reinterpret_cast<short*>(reinterpret_cast<char*>(sH1) + row * 272 + n * 2)
                    = (short)f2b(v);
            }
        }
    __syncthreads();

    f32x4 a2[3][2];
    #pragma unroll
    for (int m = 0; m < 3; ++m) { a2[m][0] = {0.f,0.f,0.f,0.f}; a2[m][1] = {0.f,0.f,0.f,0.f}; }
    #pragma unroll
    for (int ks = 0; ks < 4; ++ks) {
        int k = ks * 32 + kA;
        short8 w0 = *reinterpret_cast<const short8*>(aW2t + nc0 * EN + k);
        short8 w1 = *reinterpret_cast<const short8*>(aW2t + nc1 * EN + k);
        #pragma unroll
        for (int m = 0; m < 3; ++m) {
            short8 a = LDROW(sH1, 272, m * 16 + lr, k);
            a2[m][0] = MFMA(a, w0, a2[m][0]);
            a2[m][1] = MFMA(a, w1, a2[m][1]);
        }
    }
    {
        float b0v = ab2[nc0], b1v = ab2[nc1];
        float w3a = sW3[nc0], w3b = sW3[nc1];
        #pragma unroll
        for (int m = 0; m < 3; ++m) {
            float lp[4];
            #pragma unroll
            for (int r = 0; r < 4; ++r) {
                float v0 = fmaxf(a2[m][0][r] + b0v, 0.f);
                float v1 = fmaxf(a2[m][1][r] + b1v, 0.f);
                lp[r] = v0 * w3a + v1 * w3b;
            }
            #pragma unroll
            for (int r = 0; r < 4; ++r) {
                float v = lp[r];
                v += __shfl_xor(v, 1, 16);
                v += __shfl_xor(v, 2, 16);
                v += __shfl_xor(v, 4, 16);
                v += __shfl_xor(v, 8, 16);
                if (lr == 0) sLogP[wid][m * 16 + lq * 4 + r] = v;
            }
        }
    }
    __syncthreads();
    if (tid < 48)
        sLog[tid] = sLogP[0][tid] + sLogP[1][tid] + sLogP[2][tid] + sLogP[3][tid] + ab3[0];
    __syncthreads();

    if (tid < 64) {
        int g = tid >> 5, tt = tid & 31;
        float v = (tt < TT) ? sLog[g * TT + tt] : -1e30f;
        float mx = v;
        #pragma unroll
        for (int d = 16; d > 0; d >>= 1) mx = fmaxf(mx, __shfl_xor(mx, d, 32));
        float p = (tt < TT) ? __expf(v - mx) : 0.f;
        float s = p;
        #pragma unroll
        for (int d = 16; d > 0; d >>= 1) s += __shfl_xor(s, d, 32);
        if (tt < TT) sAtt[g * TT + tt] = p / s;
    }
    __syncthreads();

    {
        int g = tid >> 7, e = tid & 127;
        float a = 0.f;
        #pragma unroll
        for (int t = 0; t < TT; ++t) {
            unsigned short nv = *reinterpret_cast<const unsigned short*>(
                reinterpret_cast<const char*>(sNg) + (g * TT + t) * 272 + e * 2);
            a += sAtt[g * TT + t] * b2f(nv);
        }
        int node = sNode[g];
        if (owner[node] == b0 + g)
            out_embed[(size_t)node * EN + e] = a;
    }
}

extern "C" void kernel_launch(void* const* d_in, const int* in_sizes, int n_in,
                              void* d_out, int out_size, void* d_ws, size_t ws_size,
                              hipStream_t stream) {
    const int*   nodes     = (const int*)d_in[0];
    const int*   neigh_idx = (const int*)d_in[1];
    const float* u_weight  = (const float*)d_in[2];
    const float* i_weight  = (const float*)d_in[3];
    const float* uW  = (const float*)d_in[4];
    const float* ub  = (const float*)d_in[5];
    const float* iW  = (const float*)d_in[6];
    const float* ib  = (const float*)d_in[7];
    const float* aW1 = (const float*)d_in[8];
    const float* ab1 = (const float*)d_in[9];
    const float* aW2 = (const float*)d_in[10];
    const float* ab2 = (const float*)d_in[11];
    const float* aW3 = (const float*)d_in[12];
    const float* ab3 = (const float*)d_in[13];

    float* out_nf    = (float*)d_out;
    float* out_embed = out_nf + (size_t)BB * EN;

    char*  ws    = (char*)d_ws;
    short* wpack = (short*)(ws + WP_OFF);
    int*   owner = (int*)(ws + OWNER_OFF);
    short* ntab  = (short*)(ws + NTAB_OFF);
    float* npart = (float*)(ws + NPART_OFF);

    prep_kernel<<<2048, 256, 0, stream>>>(nodes, uW, iW, aW1, aW2, wpack, owner,
                                          (float4*)out_embed, NU * EN / 4);
    embed_kernel<<<NBLK_NEIGH + NBLK_NF, 256, 0, stream>>>(
        nodes, u_weight, i_weight, ub, ib, ab1, wpack, owner, ntab, out_nf, npart);
    attn_kernel<<<BB / 2, 256, 0, stream>>>(nodes, neigh_idx, ab2, aW3, ab3,
                                            wpack, ntab, npart, owner, out_embed);
}